// Round 20
// baseline (78.292 us; speedup 1.0000x reference)
//
#include <hip/hip_runtime.h>

// QuantizedLinear: out[t][o] = sum_k x[t][k] * (w_q[o][k]-128)*scale[o] + bias[o]
// M=16, N=8192, K=8192. Memory-bound on w_q (256 MB int32, read once).
//
// R20 = R18 (65.7us; = R12 64.6 within noise) + CROSS-BARRIER w-PREFETCH
// with counted vmcnt (T4). R18/R12 equality at 8 vs 16 waves/CU proved
// TLP is not the limiter; the shared flaw is that each chunk issues AND
// consumes its own w-loads, so per chunk the block's load queue fully
// drains (latency exposed once per chunk, memory idle during tail+barrier).
// Now: chunk c consumes w(c) PREFETCHED one chunk earlier (wait leaves the
// 6 newer loads flying) and the barrier waits only vmcnt(2) (retire the 4
// stage loads; w(c+1) stays in flight across the barrier). Only 8 VGPRs of
// cross-barrier state (2 int4) -- fits the proven (256,2)/128 budget,
// unlike R13's 64-reg version which spilled.
// Issue order pinned by sched_barrier(0): STAGE(c+1)[4] older than
// wpf(c+1)[2]; FMA waits on w(c) (oldest) -> vmcnt(6); barrier vmcnt(2)
// retires stage, keeps wpf flying. Manual x2 unroll for static reg naming.

#define IN_F   8192
#define OUT_F  8192
#define NT     16
#define BLOCK  256
#define W_O    2
#define CH_PER_BLOCK 8           // 4 waves * W_O
#define K_CHUNK 256
#define NCHUNK (IN_F / K_CHUNK)  // 32

typedef float f32x2 __attribute__((ext_vector_type(2)));

__global__ __launch_bounds__(BLOCK, 2)
void qlin_kernel(const float* __restrict__ x,     // [16][8192]
                 const int*   __restrict__ w_q,   // [8192][8192]
                 const float* __restrict__ scale, // [8192]
                 const float* __restrict__ bias,  // [8192]
                 float* __restrict__ out)         // [16][8192]
{
    __shared__ float xs[2][NT][K_CHUNK];          // 32 KB -> 4 blocks/CU

    const int tid  = threadIdx.x;
    const int lane = tid & 63;
    const int wave = tid >> 6;
    const int o_base = blockIdx.x * CH_PER_BLOCK + wave * W_O;

    const int* __restrict__ wr0 = w_q + (size_t)(o_base + 0) * IN_F;
    const int* __restrict__ wr1 = w_q + (size_t)(o_base + 1) * IN_F;

    // Stage x chunk c (16 KB = 16 rows x 1024 B) into LDS buf b. 4 rounds;
    // wave w stages row r*4+w; LDS dest wave-uniform (+lane*16 by HW).
#define STAGE(c, b)                                                          \
    {                                                                        \
        _Pragma("unroll")                                                    \
        for (int r = 0; r < 4; ++r) {                                        \
            const int row = r * 4 + wave;                                    \
            const char* g = (const char*)x + (size_t)row * (IN_F * 4) +      \
                            (size_t)(c) * 1024 + lane * 16;                  \
            char* l = (char*)(&xs[0][0][0]) + (b) * 16384 + row * 1024;      \
            __builtin_amdgcn_global_load_lds(                                \
                (const __attribute__((address_space(1))) void*)g,            \
                (__attribute__((address_space(3))) void*)l, 16, 0, 0);       \
        }                                                                    \
    }

    // Prefetch chunk c's two w-vectors into named regs (8 VGPRs).
#define WPF(WA, WB, c)                                                       \
    WA = *reinterpret_cast<const int4*>(wr0 + (c) * K_CHUNK + lane * 4);     \
    WB = *reinterpret_cast<const int4*>(wr1 + (c) * K_CHUNK + lane * 4);

    // One 256-wide k-step from prefetched regs + LDS x.
#define FMA(WA, WB, cur)                                                     \
    {                                                                        \
        f32x2 wf[4];                                                         \
        wf[0] = (f32x2){(float)(WA.x - 128), (float)(WB.x - 128)};           \
        wf[1] = (f32x2){(float)(WA.y - 128), (float)(WB.y - 128)};           \
        wf[2] = (f32x2){(float)(WA.z - 128), (float)(WB.z - 128)};           \
        wf[3] = (f32x2){(float)(WA.w - 128), (float)(WB.w - 128)};           \
        _Pragma("unroll")                                                    \
        for (int t = 0; t < NT; ++t) {                                       \
            const float4 xv = *reinterpret_cast<const float4*>(              \
                &xs[cur][t][lane * 4]);                                      \
            acc2[t] += wf[0] * (f32x2){xv.x, xv.x};                          \
            acc2[t] += wf[1] * (f32x2){xv.y, xv.y};                          \
            acc2[t] += wf[2] * (f32x2){xv.z, xv.z};                          \
            acc2[t] += wf[3] * (f32x2){xv.w, xv.w};                          \
        }                                                                    \
    }

    // One chunk: stage+prefetch next (pinned order), compute current from
    // chunk-old regs, then barrier that retires ONLY the stage loads.
#define CHUNK(c, WA_CUR, WB_CUR, WA_NXT, WB_NXT)                             \
    {                                                                        \
        if ((c) + 1 < NCHUNK) {                                              \
            STAGE((c) + 1, ((c) & 1) ^ 1)                                    \
            __builtin_amdgcn_sched_barrier(0);                               \
            WPF(WA_NXT, WB_NXT, (c) + 1)                                     \
        }                                                                    \
        __builtin_amdgcn_sched_barrier(0);                                   \
        FMA(WA_CUR, WB_CUR, (c) & 1)                                         \
        __builtin_amdgcn_sched_barrier(0);                                   \
        if ((c) + 1 < NCHUNK) {                                              \
            asm volatile("s_waitcnt vmcnt(2) lgkmcnt(0)" ::: "memory");      \
            __builtin_amdgcn_s_barrier();                                    \
            __builtin_amdgcn_sched_barrier(0);                               \
        }                                                                    \
    }

    f32x2 acc2[NT];   // 32 VGPRs
#pragma unroll
    for (int t = 0; t < NT; ++t) acc2[t] = (f32x2)0.0f;

    int4 a0, a1, b0, b1;   // double-buffered w prefetch (8 VGPRs live)

    // prologue: stage(0) [4 oldest] then wpf(0) [2]; vmcnt(2) retires stage.
    STAGE(0, 0)
    __builtin_amdgcn_sched_barrier(0);
    WPF(a0, a1, 0)
    __builtin_amdgcn_sched_barrier(0);
    asm volatile("s_waitcnt vmcnt(2)" ::: "memory");
    __builtin_amdgcn_s_barrier();
    __builtin_amdgcn_sched_barrier(0);

#pragma unroll 1
    for (int cc = 0; cc < NCHUNK; cc += 2) {
        CHUNK(cc + 0, a0, a1, b0, b1)
        CHUNK(cc + 1, b0, b1, a0, a1)
    }

#undef STAGE
#undef WPF
#undef FMA
#undef CHUNK

    // ---- cross-lane reduction: 32 (t,j) values, 6-step butterfly each ----
    float myval = 0.0f;
#pragma unroll
    for (int t = 0; t < NT; ++t) {
#pragma unroll
        for (int j = 0; j < W_O; ++j) {
            float v = acc2[t][j];
#pragma unroll
            for (int off = 32; off > 0; off >>= 1)
                v += __shfl_xor(v, off, 64);
            if (lane == (t * W_O + j)) myval = v;
        }
    }

    // lane l (<32) -> t = l>>1, channel j = l&1
    if (lane < NT * W_O) {
        const int t_o = lane >> 1;
        const int o   = o_base + (lane & 1);
        out[(size_t)t_o * OUT_F + o] = myval * scale[o] + bias[o];
    }
}

extern "C" void kernel_launch(void* const* d_in, const int* in_sizes, int n_in,
                              void* d_out, int out_size, void* d_ws, size_t ws_size,
                              hipStream_t stream) {
    const float* x     = (const float*)d_in[0];
    const int*   w_q   = (const int*)d_in[1];
    const float* scale = (const float*)d_in[2];
    const float* bias  = (const float*)d_in[3];
    float*       out   = (float*)d_out;

    dim3 grid(OUT_F / CH_PER_BLOCK);   // 1024 blocks -> 4/CU, 16 waves/CU
    dim3 block(BLOCK);
    qlin_kernel<<<grid, block, 0, stream>>>(x, w_q, scale, bias, out);
}

// Round 21
// 67.581 us; speedup vs baseline: 1.1585x; 1.1585x over previous
//
#include <hip/hip_runtime.h>

// QuantizedLinear: out[t][o] = sum_k x[t][k] * (w_q[o][k]-128)*scale[o] + bias[o]
// M=16, N=8192, K=8192. Memory-bound on w_q (256 MB int32, read once).
//
// R21: TRUE deep pipeline -- nothing waits on same-chunk loads.
// R12/R18/R20 all drained the load queue once per chunk (R18: FMA waits
// same-chunk w; R20: barrier waits same-chunk stage). Now: x staged TWO
// chunks ahead (4 LDS buffers), w prefetched ONE chunk ahead (8 VGPRs).
// Per chunk: issue stage(c+2)[2 gld_lds] + wpf(c+1)[2]; FMA(c)'s operand
// wait = vmcnt(4), which by in-order retirement also retires stage(c+1)
// (for next chunk's readers) and wpf(c) -- so the barrier needs ONLY
// lgkmcnt(0). No explicit vmcnt anywhere in the loop; >=4 loads always in
// flight. Cross-wave publish: each wave's own vmcnt(4) retires its older
// stage loads before it reaches the barrier.
// Geometry: NBUF=4 x K_CHUNK=128 -> 32 KB LDS, BLOCK=256 (256,2) [the only
// allocator-sane config, R10-R14], W_O=2, grid 1024 -> uniform 4 blocks/CU,
// 16 waves/CU. Cross-barrier reg state 8 VGPRs (live ~80, no spill).

#define IN_F   8192
#define OUT_F  8192
#define NT     16
#define BLOCK  256
#define W_O    2
#define CH_PER_BLOCK 8           // 4 waves * W_O
#define K_CHUNK 128
#define NCHUNK (IN_F / K_CHUNK)  // 64
#define NBUF   4

typedef float f32x2 __attribute__((ext_vector_type(2)));

__global__ __launch_bounds__(BLOCK, 2)
void qlin_kernel(const float* __restrict__ x,     // [16][8192]
                 const int*   __restrict__ w_q,   // [8192][8192]
                 const float* __restrict__ scale, // [8192]
                 const float* __restrict__ bias,  // [8192]
                 float* __restrict__ out)         // [16][8192]
{
    __shared__ float xs[NBUF][NT][K_CHUNK];       // 32 KB -> 4 blocks/CU

    const int tid  = threadIdx.x;
    const int lane = tid & 63;
    const int wave = tid >> 6;
    const int o_base = blockIdx.x * CH_PER_BLOCK + wave * W_O;

    const int* __restrict__ wr0 = w_q + (size_t)(o_base + 0) * IN_F;
    const int* __restrict__ wr1 = w_q + (size_t)(o_base + 1) * IN_F;

    // Stage x chunk c (8 KB = 16 rows x 512 B) into LDS buf b.
    // Per wave: 2 x 1KB gld_lds; segment seg = wave*2+i covers rows
    // {2seg, 2seg+1}: global row = 2seg + (lane>>5), byte (lane&31)*16;
    // LDS dest wave-uniform base + lane*16 (HW-added) = linear row pair.
#define STAGE(c, b)                                                          \
    {                                                                        \
        _Pragma("unroll")                                                    \
        for (int i = 0; i < 2; ++i) {                                        \
            const int seg = wave * 2 + i;                                    \
            const int row = seg * 2 + (lane >> 5);                           \
            const char* g = (const char*)x + (size_t)row * (IN_F * 4) +      \
                            (size_t)(c) * (K_CHUNK * 4) + (lane & 31) * 16;  \
            char* l = (char*)(&xs[0][0][0]) + (b) * (NT * K_CHUNK * 4) +     \
                      seg * 1024;                                            \
            __builtin_amdgcn_global_load_lds(                                \
                (const __attribute__((address_space(1))) void*)g,            \
                (__attribute__((address_space(3))) void*)l, 16, 0, 0);       \
        }                                                                    \
    }

    // Prefetch chunk c's two w int2 vectors (4 VGPRs).
#define WPF(WA, WB, c)                                                       \
    WA = *reinterpret_cast<const int2*>(wr0 + (c) * K_CHUNK + lane * 2);     \
    WB = *reinterpret_cast<const int2*>(wr1 + (c) * K_CHUNK + lane * 2);

    // One 128-wide k-step from prefetched regs + LDS x.
#define FMA(WA, WB, b)                                                       \
    {                                                                        \
        const f32x2 wf0 = (f32x2){(float)(WA.x - 128), (float)(WB.x - 128)}; \
        const f32x2 wf1 = (f32x2){(float)(WA.y - 128), (float)(WB.y - 128)}; \
        _Pragma("unroll")                                                    \
        for (int t = 0; t < NT; ++t) {                                       \
            const float2 xv = *reinterpret_cast<const float2*>(              \
                &xs[b][t][lane * 2]);                                        \
            acc2[t] += wf0 * (f32x2){xv.x, xv.x};                            \
            acc2[t] += wf1 * (f32x2){xv.y, xv.y};                            \
        }                                                                    \
    }

    // Chunk: stage 2-ahead, prefetch 1-ahead (issue order pinned), compute
    // from chunk-old regs, barrier with lgkm-only wait (no vmcnt!).
#define CHUNK(c, WA_CUR, WB_CUR, WA_NXT, WB_NXT)                             \
    {                                                                        \
        if ((c) + 2 < NCHUNK) STAGE((c) + 2, ((c) + 2) & 3)                  \
        __builtin_amdgcn_sched_barrier(0);                                   \
        if ((c) + 1 < NCHUNK) { WPF(WA_NXT, WB_NXT, (c) + 1) }               \
        __builtin_amdgcn_sched_barrier(0);                                   \
        FMA(WA_CUR, WB_CUR, (c) & 3)                                         \
        __builtin_amdgcn_sched_barrier(0);                                   \
        if ((c) + 1 < NCHUNK) {                                              \
            asm volatile("s_waitcnt lgkmcnt(0)" ::: "memory");               \
            __builtin_amdgcn_s_barrier();                                    \
            __builtin_amdgcn_sched_barrier(0);                               \
        }                                                                    \
    }

    f32x2 acc2[NT];   // 32 VGPRs
#pragma unroll
    for (int t = 0; t < NT; ++t) acc2[t] = (f32x2)0.0f;

    int2 a0, a1, b0, b1;   // w prefetch, double-buffered (8 VGPRs)

    // prologue: stage(0), stage(1) [2+2 oldest], wpf(0) [2]; vmcnt(4)
    // retires stage(0) only -- stage(1)+wpf(0) stay in flight.
    STAGE(0, 0)
    __builtin_amdgcn_sched_barrier(0);
    STAGE(1, 1)
    __builtin_amdgcn_sched_barrier(0);
    WPF(a0, a1, 0)
    __builtin_amdgcn_sched_barrier(0);
    asm volatile("s_waitcnt vmcnt(4)" ::: "memory");
    __builtin_amdgcn_s_barrier();
    __builtin_amdgcn_sched_barrier(0);

#pragma unroll 1
    for (int cc = 0; cc < NCHUNK; cc += 2) {
        CHUNK(cc + 0, a0, a1, b0, b1)
        CHUNK(cc + 1, b0, b1, a0, a1)
    }

#undef STAGE
#undef WPF
#undef FMA
#undef CHUNK

    // ---- cross-lane reduction: 32 (t,j) values, 6-step butterfly each ----
    float myval = 0.0f;
#pragma unroll
    for (int t = 0; t < NT; ++t) {
#pragma unroll
        for (int j = 0; j < W_O; ++j) {
            float v = acc2[t][j];
#pragma unroll
            for (int off = 32; off > 0; off >>= 1)
                v += __shfl_xor(v, off, 64);
            if (lane == (t * W_O + j)) myval = v;
        }
    }

    // lane l (<32) -> t = l>>1, channel j = l&1
    if (lane < NT * W_O) {
        const int t_o = lane >> 1;
        const int o   = o_base + (lane & 1);
        out[(size_t)t_o * OUT_F + o] = myval * scale[o] + bias[o];
    }
}

extern "C" void kernel_launch(void* const* d_in, const int* in_sizes, int n_in,
                              void* d_out, int out_size, void* d_ws, size_t ws_size,
                              hipStream_t stream) {
    const float* x     = (const float*)d_in[0];
    const int*   w_q   = (const int*)d_in[1];
    const float* scale = (const float*)d_in[2];
    const float* bias  = (const float*)d_in[3];
    float*       out   = (float*)d_out;

    dim3 grid(OUT_F / CH_PER_BLOCK);   // 1024 blocks -> uniform 4/CU
    dim3 block(BLOCK);
    qlin_kernel<<<grid, block, 0, stream>>>(x, w_q, scale, bias, out);
}